// Round 6
// baseline (437.371 us; speedup 1.0000x reference)
//
#include <hip/hip_runtime.h>
#include <math.h>

// Problem constants (B=4, S=4096, H=4096, E=64, top_k=8)
#define H_DIM  4096
#define E_NUM  64
#define N_TOK  16384          // B*S
#define TPB    64             // tokens per block
#define KC     128            // K chunk (v6: doubled -> 32 chunks, half the barriers)
#define NCHUNK (H_DIM / KC)   // 32
#define TOPK   8

// flat output layout: [probs (N_TOK*64)][indices (N_TOK*8)][gate (N_TOK*64)]
#define N_PROBS  (N_TOK * E_NUM)          // 1048576
#define N_IDX    (N_TOK * TOPK)           // 131072
#define OFF_IDX  N_PROBS
#define OFF_GATE (N_PROBS + N_IDX)        // 1179648

// v6b: v6 with the compile fix — cvt_pkrtz and the f16 MFMA builtins are
// typed on __fp16 vectors (clang: 'V8h'), not _Float16. Logic unchanged:
// fp16 pair-split (4 MFMA products hh,hl,lh,ll; was 6 bf16) +
// global_load_lds staging of RAW fp32 tiles (swizzle baked into the per-lane
// SOURCE address; LDS dest linear; reads apply the same XOR -> rule-21
// involution). cvt fp32->fp16x2 at frag-load via v_cvt_pkrtz (1 instr/2 elems).
// 256 threads, launch_bounds(256,1): the proven no-spill regime.
// Numerics: x*2^6, W*2^8 (exact scales, clears fp16 denormals), hi=RTZ(f),
// lo=RTZ(f-hi) -> per-product err <= 2^-22|xw|, summed ~1e-8. 4 independent
// fp32 acc chains, fp64 fold every 2 chunks (16-add chains ~6e-8) -> same
// error class as every passing version.

typedef __attribute__((ext_vector_type(8))) __fp16 half8;    // 4 VGPR
typedef __attribute__((ext_vector_type(2))) __fp16 half2t;
typedef __attribute__((ext_vector_type(16))) float f32x16;   // 32x32 acc

#define XSCALE 64.0f
#define WSCALE 256.0f
#define DESCALE (1.0 / 16384.0)

__global__ __launch_bounds__(256, 1)
void gating_kernel(const float* __restrict__ x, const float* __restrict__ W,
                   float* __restrict__ out) {
  // Raw fp32 tiles [64 rows][128 k], double-buffered, x + W = 128 KB.
  // Row = 512 B; frag reads are 32 B per lane at kbyte ^ ((row&15)<<5).
  // lg overlays the tiles after the GEMM for the epilogue.
  __shared__ union __align__(16) {
    struct { float xs[2][64][KC]; float ws[2][64][KC]; } t;   // 131072 B
    float lg[TPB][E_NUM + 1];                                 // stride 65
  } u;

  const int tid  = threadIdx.x;
  const int tok0 = blockIdx.x * TPB;
  const int lane = tid & 63;
  const int wid  = tid >> 6;            // 0..3
  const int wm   = wid >> 1;            // token half  (32 tokens)
  const int wn   = wid & 1;             // expert half (32 experts)
  const int l31  = lane & 31;
  const int arow = 32 * wm + l31;       // token row for A frags
  const int brow = 32 * wn + l31;       // expert row for B frags
  const int khalf = 32 * (lane >> 5);   // byte offset of this lane's k-octet

  const float* xg = x + (size_t)tok0 * H_DIM;

  // Stage one 32 KB fp32 tile via global_load_lds (width 16). Linear LDS
  // offset o = I*1024 + lane*16 -> row = 2I + (lane>>5), lin = (lane&31)*16.
  // Source byte = rowbase + cbyte + (lin ^ ((row&15)<<5))  [swizzle baked].
  auto stage = [&](const float* gbase, float* lds, int cbyte) {
#pragma unroll
    for (int i = 0; i < 8; ++i) {
      const int I   = wid * 8 + i;                  // wave-uniform
      const int row = 2 * I + (lane >> 5);
      const int lin = (lane & 31) * 16;
      const char* src = (const char*)(gbase + (size_t)row * H_DIM) + cbyte
                        + (lin ^ ((row & 15) << 5));
      __builtin_amdgcn_global_load_lds(
          (const __attribute__((address_space(1))) unsigned int*)src,
          (__attribute__((address_space(3))) unsigned int*)((char*)lds + I * 1024),
          16, 0, 0);
    }
  };

  // swizzled frag pointer: 8 consecutive fp32 (32 B) for (row, k-tile kt)
  auto fragp = [&](const float* base, int row, int kt) -> const float* {
    const int kbyte = kt * 64 + khalf;
    return (const float*)((const char*)base + row * 512
                          + (kbyte ^ ((row & 15) << 5)));
  };

  // fp32x8 -> (hi, lo) fp16x8 via pkrtz; rem computed exactly in fp32.
  auto split8 = [&](const float* p, float scale, half8& hi, half8& lo) {
    const float4 v0 = ((const float4*)p)[0];
    const float4 v1 = ((const float4*)p)[1];
    float f[8] = {v0.x, v0.y, v0.z, v0.w, v1.x, v1.y, v1.z, v1.w};
#pragma unroll
    for (int i = 0; i < 8; ++i) f[i] *= scale;   // exact (power of 2)
#pragma unroll
    for (int i = 0; i < 4; ++i) {
      half2t h = __builtin_amdgcn_cvt_pkrtz(f[2 * i], f[2 * i + 1]);
      const float r0 = f[2 * i]     - (float)h.x;   // exact remainder
      const float r1 = f[2 * i + 1] - (float)h.y;
      half2t l = __builtin_amdgcn_cvt_pkrtz(r0, r1);
      hi[2 * i] = h.x; hi[2 * i + 1] = h.y;
      lo[2 * i] = l.x; lo[2 * i + 1] = l.y;
    }
  };

  stage(xg, &u.t.xs[0][0][0], 0);
  stage(W,  &u.t.ws[0][0][0], 0);
  __syncthreads();   // compiler drains vmcnt before s_barrier -> tiles ready

  // 4 independent product chains (hh,hl,lh,ll): no MFMA dep stalls.
  f32x16 aHH, aHL, aLH, aLL;
  double accd[16];
#pragma unroll
  for (int r = 0; r < 16; ++r) {
    aHH[r] = 0.f; aHL[r] = 0.f; aLH[r] = 0.f; aLL[r] = 0.f; accd[r] = 0.0;
  }

  for (int c = 0; c < NCHUNK; ++c) {
    const int b = c & 1;
    if (c + 1 < NCHUNK) {
      // T3 order: issue next-tile staging BEFORE compute. Writes target
      // buf b^1 whose last readers finished before the barrier that ended
      // iteration c-1 -> one barrier per chunk suffices.
      const int cb = (c + 1) * KC * 4;
      stage(xg, &u.t.xs[b ^ 1][0][0], cb);
      stage(W,  &u.t.ws[b ^ 1][0][0], cb);
    }
    const float* xt = &u.t.xs[b][0][0];
    const float* wt = &u.t.ws[b][0][0];

#pragma unroll
    for (int kt = 0; kt < KC / 16; ++kt) {   // 8 k-tiles of 16
      half8 ah, al, bh, bl;
      split8(fragp(xt, arow, kt), XSCALE, ah, al);
      split8(fragp(wt, brow, kt), WSCALE, bh, bl);
      aHH = __builtin_amdgcn_mfma_f32_32x32x16_f16(ah, bh, aHH, 0, 0, 0);
      aHL = __builtin_amdgcn_mfma_f32_32x32x16_f16(ah, bl, aHL, 0, 0, 0);
      aLH = __builtin_amdgcn_mfma_f32_32x32x16_f16(al, bh, aLH, 0, 0, 0);
      aLL = __builtin_amdgcn_mfma_f32_32x32x16_f16(al, bl, aLL, 0, 0, 0);
    }

    if (c & 1) {   // fp64 fold every 2 chunks (256 k): 16-add fp32 chains
#pragma unroll
      for (int r = 0; r < 16; ++r) {
        accd[r] += (double)aHH[r] + (double)aHL[r]
                 + (double)aLH[r] + (double)aLL[r];
        aHH[r] = 0.f; aHL[r] = 0.f; aLH[r] = 0.f; aLL[r] = 0.f;
      }
    }

    __syncthreads();   // drains stage writes (b^1) + fences reads of b
  }

  // C/D layout (HW-verified m74/m101): col = lane&31,
  // row = (reg&3) + 8*(reg>>2) + 4*(lane>>5).
  const int rb = 4 * (lane >> 5);
  float* gate = out + OFF_GATE;
#pragma unroll
  for (int q = 0; q < 4; ++q)
#pragma unroll
    for (int j = 0; j < 4; ++j) {
      const int reg   = 4 * q + j;
      const int row32 = j + 8 * q + rb;
      const float v   = (float)(accd[reg] * DESCALE);   // exact 2^-14
      const int trow  = 32 * wm + row32;
      const int e     = 32 * wn + l31;
      gate[(size_t)(tok0 + trow) * E_NUM + e] = v;   // coalesced 128B/half-wave
      u.lg[trow][e] = v;   // overlay is safe: loop's final barrier passed
    }
  __syncthreads();

  // Phase 2: one thread per token — verbatim from the verified kernel
  // (strict > == jax lowest-index tie-break).
  if (tid < TPB) {
    const int t = tid;
    float vals[TOPK];
    int   idxs[TOPK];
#pragma unroll
    for (int p = 0; p < TOPK; ++p) {
      float best = -INFINITY;
      int   bi   = 0;
      for (int e = 0; e < E_NUM; ++e) {
        const float v = u.lg[t][e];
        if (v > best) { best = v; bi = e; }
      }
      vals[p] = best;
      idxs[p] = bi;
      u.lg[t][bi] = -INFINITY;
    }
    const float m = vals[0];
    float s = 0.f, pr[TOPK];
#pragma unroll
    for (int p = 0; p < TOPK; ++p) { pr[p] = __expf(vals[p] - m); s += pr[p]; }
    const float inv = 1.0f / s;
    for (int e = 0; e < E_NUM; ++e) u.lg[t][e] = 0.f;
#pragma unroll
    for (int p = 0; p < TOPK; ++p) u.lg[t][idxs[p]] = pr[p] * inv;

    float* oidx = out + OFF_IDX + (size_t)(tok0 + t) * TOPK;
#pragma unroll
    for (int p = 0; p < TOPK; ++p) oidx[p] = (float)idxs[p];
  }
  __syncthreads();

  // coalesced writeback of the sparse_probs rows
  float* oprob = out + (size_t)tok0 * E_NUM;
#pragma unroll
  for (int p = 0; p < 16; ++p) {
    const int f = tid + 256 * p;
    oprob[f] = u.lg[f >> 6][f & 63];
  }
}

extern "C" void kernel_launch(void* const* d_in, const int* in_sizes, int n_in,
                              void* d_out, int out_size, void* d_ws, size_t ws_size,
                              hipStream_t stream) {
  const float* x = (const float*)d_in[0];
  const float* W = (const float*)d_in[1];
  float* out = (float*)d_out;
  dim3 grid(N_TOK / TPB);   // 256 blocks -> 1 per CU
  dim3 block(256);          // 4 waves: (token-half, expert-half), full K each
  gating_kernel<<<grid, block, 0, stream>>>(x, W, out);
}

// Round 7
// 422.650 us; speedup vs baseline: 1.0348x; 1.0348x over previous
//
#include <hip/hip_runtime.h>
#include <math.h>

// Problem constants (B=4, S=4096, H=4096, E=64, top_k=8)
#define H_DIM  4096
#define E_NUM  64
#define N_TOK  16384          // B*S
#define TPB    64             // tokens per block
#define KC     128            // K chunk (32 chunks)
#define NCHUNK (H_DIM / KC)   // 32
#define TOPK   8

// flat output layout: [probs (N_TOK*64)][indices (N_TOK*8)][gate (N_TOK*64)]
#define N_PROBS  (N_TOK * E_NUM)          // 1048576
#define N_IDX    (N_TOK * TOPK)           // 131072
#define OFF_IDX  N_PROBS
#define OFF_GATE (N_PROBS + N_IDX)        // 1179648

// v7: v6b counters showed MFMA 13us + VALU 40us + conflicts 7us inside 192us
// -> ~70% exposed latency at 1 wave/SIMD. Fix jointly:
//  (a) 512 threads, in-block k-split-2 -> 8 waves = 2/SIMD (v5's spill trap
//      avoided by a register diet: 2 MFMA chains not 4, uint-packed half8
//      assembly; live state ~100 VGPR under the bounds(512,2)=128 cap).
//  (b) conflict-free swizzle: per-16B-unit XOR (row&7)<<4 (involution baked
//      into the global_load_lds SOURCE address; frag reads apply same XOR).
//      Phase-mate rows hit distinct bank groups -> b128 reads conflict-free.
// Numerics (same class as every passing version): x*2^6, W*2^8 exact scales;
// hi=RTZ(f), lo=RTZ(f-hi) -> product err <=2^-22|xw|; 2 fp32 chains folded
// to fp64 every 2 chunks (16-add windows); cross-group fp64 reduce via LDS.

typedef __attribute__((ext_vector_type(8))) __fp16 half8;    // 4 VGPR
typedef __attribute__((ext_vector_type(2))) __fp16 half2t;
typedef __attribute__((ext_vector_type(16))) float f32x16;   // 32x32 acc
typedef __attribute__((ext_vector_type(4))) unsigned int uint4v;

#define XSCALE 64.0f
#define WSCALE 256.0f
#define DESCALE (1.0 / 16384.0)

__global__ __launch_bounds__(512, 2)
void gating_kernel(const float* __restrict__ x, const float* __restrict__ W,
                   float* __restrict__ out) {
  // Raw fp32 tiles [64 rows][128 k], double-buffered, x + W = 128 KB.
  // Overlays: fp64 cross-group dump @ +64 KB, epilogue lg @ 0.
  __shared__ union __align__(16) {
    struct { float xs[2][64][KC]; float ws[2][64][KC]; } t;   // 131072 B
    struct { float pad[16384]; double dump[4][16][64]; } r;   // 32 KB @ +64 KB
    float lg[TPB][E_NUM + 1];                                 // stride 65
  } u;

  const int tid  = threadIdx.x;
  const int tok0 = blockIdx.x * TPB;
  const int lane = tid & 63;
  const int wid  = tid >> 6;            // 0..7
  const int g    = wid >> 2;            // k-half group: kt 0-3 or 4-7
  const int sub  = wid & 3;             // output tile id
  const int wm   = sub >> 1;            // token half  (32 tokens)
  const int wn   = sub & 1;             // expert half (32 experts)
  const int l31  = lane & 31;
  const int arow = 32 * wm + l31;       // token row for A frags
  const int brow = 32 * wn + l31;       // expert row for B frags
  const int khalf = 32 * (lane >> 5);   // byte offset of this lane's k-octet

  const float* xg = x + (size_t)tok0 * H_DIM;

  // Stage one 32 KB fp32 tile via global_load_lds (width 16), 4 instr/thread.
  // Linear LDS: instr I=(i*8+wid) covers rows 2I,2I+1; dest = I*1024 + lane*16.
  // Source byte = rowbase + cbyte + (lin ^ ((row&7)<<4))   [swizzle baked].
  auto stage = [&](const float* gbase, float* lds, int cbyte) {
#pragma unroll
    for (int i = 0; i < 4; ++i) {
      const int I   = i * 8 + wid;                  // wave-uniform
      const int row = 2 * I + (lane >> 5);
      const int lin = (lane & 31) * 16;
      const char* src = (const char*)(gbase + (size_t)row * H_DIM) + cbyte
                        + (lin ^ ((row & 7) << 4));
      __builtin_amdgcn_global_load_lds(
          (const __attribute__((address_space(1))) unsigned int*)src,
          (__attribute__((address_space(3))) unsigned int*)((char*)lds + I * 1024),
          16, 0, 0);
    }
  };

  // swizzled 16B frag unit at in-row byte q (applies the same involution)
  auto frag16 = [&](const float* base, int row, int q) -> float4 {
    return *(const float4*)((const char*)base + row * 512
                            + (q ^ ((row & 7) << 4)));
  };

  // fp32x8 -> (hi,lo) fp16x8 via pkrtz; half8 assembled by uint bit-pack
  // (pkrtz output is already a packed 32-bit reg -> no element-insert storm).
  auto split8 = [&](float4 v0, float4 v1, float scale, half8& hi, half8& lo) {
    const float f[8] = {v0.x, v0.y, v0.z, v0.w, v1.x, v1.y, v1.z, v1.w};
    unsigned hu[4], lu[4];
#pragma unroll
    for (int i = 0; i < 4; ++i) {
      const float a = f[2 * i] * scale;       // exact (power of 2)
      const float b = f[2 * i + 1] * scale;
      half2t h = __builtin_amdgcn_cvt_pkrtz(a, b);
      const float r0 = a - (float)h.x;        // exact remainder
      const float r1 = b - (float)h.y;
      half2t l = __builtin_amdgcn_cvt_pkrtz(r0, r1);
      hu[i] = __builtin_bit_cast(unsigned, h);
      lu[i] = __builtin_bit_cast(unsigned, l);
    }
    hi = __builtin_bit_cast(half8, (uint4v){hu[0], hu[1], hu[2], hu[3]});
    lo = __builtin_bit_cast(half8, (uint4v){lu[0], lu[1], lu[2], lu[3]});
  };

  stage(xg, &u.t.xs[0][0][0], 0);
  stage(W,  &u.t.ws[0][0][0], 0);
  __syncthreads();   // compiler drains vmcnt before s_barrier -> tiles ready

  // 2 MFMA chains (aH: hh+hl, aL: lh+ll) -> 32 acc VGPRs; fp64 fold every
  // 2 chunks (16-add fp32 windows, v1-class error).
  f32x16 aH, aL;
  double accd[16];
#pragma unroll
  for (int r = 0; r < 16; ++r) { aH[r] = 0.f; aL[r] = 0.f; accd[r] = 0.0; }

  for (int c = 0; c < NCHUNK; ++c) {
    const int b = c & 1;
    if (c + 1 < NCHUNK) {
      // issue next-tile staging BEFORE compute; writes target buf b^1 whose
      // last readers finished before the barrier ending iteration c-1.
      const int cb = (c + 1) * KC * 4;
      stage(xg, &u.t.xs[b ^ 1][0][0], cb);
      stage(W,  &u.t.ws[b ^ 1][0][0], cb);
    }
    const float* xt = &u.t.xs[b][0][0];
    const float* wt = &u.t.ws[b][0][0];

#pragma unroll
    for (int kt = 0; kt < 4; ++kt) {         // this group's 4 k-tiles of 16
      const int q = (4 * g + kt) * 64 + khalf;
      half8 ah, al, bh, bl;
      split8(frag16(xt, arow, q), frag16(xt, arow, q + 16), XSCALE, ah, al);
      split8(frag16(wt, brow, q), frag16(wt, brow, q + 16), WSCALE, bh, bl);
      aH = __builtin_amdgcn_mfma_f32_32x32x16_f16(ah, bh, aH, 0, 0, 0);
      aL = __builtin_amdgcn_mfma_f32_32x32x16_f16(al, bh, aL, 0, 0, 0);
      aH = __builtin_amdgcn_mfma_f32_32x32x16_f16(ah, bl, aH, 0, 0, 0);
      aL = __builtin_amdgcn_mfma_f32_32x32x16_f16(al, bl, aL, 0, 0, 0);
    }

    if (c & 1) {   // fp64 fold every 2 chunks
#pragma unroll
      for (int r = 0; r < 16; ++r) {
        accd[r] += (double)aH[r] + (double)aL[r];
        aH[r] = 0.f; aL[r] = 0.f;
      }
    }

    __syncthreads();   // drains stage writes (b^1) + fences reads of b
  }
  __syncthreads();   // all frag reads done before the dump overlays the tiles

  // cross-k-group fp64 reduce: g1 dumps, g0 adds. Lanes write consecutive
  // 8B words -> 2-way bank aliasing = free.
  if (g == 1) {
#pragma unroll
    for (int r = 0; r < 16; ++r) u.r.dump[sub][r][lane] = accd[r];
  }
  __syncthreads();

  if (g == 0) {
    // C/D layout (HW-verified m74/m101): col = lane&31,
    // row = (reg&3) + 8*(reg>>2) + 4*(lane>>5).
    const int rb = 4 * (lane >> 5);
    float* gate = out + OFF_GATE;
#pragma unroll
    for (int q = 0; q < 4; ++q)
#pragma unroll
      for (int j = 0; j < 4; ++j) {
        const int reg   = 4 * q + j;
        const int row32 = j + 8 * q + rb;
        const float v   = (float)((accd[reg] + u.r.dump[sub][reg][lane]) * DESCALE);
        const int trow  = 32 * wm + row32;
        const int e     = 32 * wn + l31;
        gate[(size_t)(tok0 + trow) * E_NUM + e] = v;   // coalesced 128B/half-wave
        u.lg[trow][e] = v;    // lg (@0..16.6KB) disjoint from dump (@64KB)
      }
  }
  __syncthreads();

  // Phase 2: one thread per token — verbatim from the verified kernel
  // (strict > == jax lowest-index tie-break).
  if (tid < TPB) {
    const int t = tid;
    float vals[TOPK];
    int   idxs[TOPK];
#pragma unroll
    for (int p = 0; p < TOPK; ++p) {
      float best = -INFINITY;
      int   bi   = 0;
      for (int e = 0; e < E_NUM; ++e) {
        const float v = u.lg[t][e];
        if (v > best) { best = v; bi = e; }
      }
      vals[p] = best;
      idxs[p] = bi;
      u.lg[t][bi] = -INFINITY;
    }
    const float m = vals[0];
    float s = 0.f, pr[TOPK];
#pragma unroll
    for (int p = 0; p < TOPK; ++p) { pr[p] = __expf(vals[p] - m); s += pr[p]; }
    const float inv = 1.0f / s;
    for (int e = 0; e < E_NUM; ++e) u.lg[t][e] = 0.f;
#pragma unroll
    for (int p = 0; p < TOPK; ++p) u.lg[t][idxs[p]] = pr[p] * inv;

    float* oidx = out + OFF_IDX + (size_t)(tok0 + t) * TOPK;
#pragma unroll
    for (int p = 0; p < TOPK; ++p) oidx[p] = (float)idxs[p];
  }
  __syncthreads();

  // coalesced writeback of the sparse_probs rows (512 threads x 8)
  float* oprob = out + (size_t)tok0 * E_NUM;
#pragma unroll
  for (int p = 0; p < 8; ++p) {
    const int f = tid + 512 * p;
    oprob[f] = u.lg[f >> 6][f & 63];
  }
}

extern "C" void kernel_launch(void* const* d_in, const int* in_sizes, int n_in,
                              void* d_out, int out_size, void* d_ws, size_t ws_size,
                              hipStream_t stream) {
  const float* x = (const float*)d_in[0];
  const float* W = (const float*)d_in[1];
  float* out = (float*)d_out;
  dim3 grid(N_TOK / TPB);   // 256 blocks -> 1 per CU
  dim3 block(512);          // 8 waves = 2/SIMD: (k-half, token-half, expert-half)
  gating_kernel<<<grid, block, 0, stream>>>(x, W, out);
}

// Round 8
// 401.743 us; speedup vs baseline: 1.0887x; 1.0520x over previous
//
#include <hip/hip_runtime.h>
#include <math.h>

// Problem constants (B=4, S=4096, H=4096, E=64, top_k=8)
#define H_DIM  4096
#define E_NUM  64
#define N_TOK  16384          // B*S
#define TPB    64             // tokens per block
#define KC     64             // K chunk (64 chunks; 32 KB staged per chunk)
#define NCHUNK (H_DIM / KC)   // 64
#define TOPK   8

// flat output layout: [probs (N_TOK*64)][indices (N_TOK*8)][gate (N_TOK*64)]
#define N_PROBS  (N_TOK * E_NUM)          // 1048576
#define N_IDX    (N_TOK * TOPK)           // 131072
#define OFF_IDX  N_PROBS
#define OFF_GATE (N_PROBS + N_IDX)        // 1179648

// v8: counted-vmcnt pipeline (T3/T4). v7 post-mortem: conflicts identical
// across different read swizzles -> conflicts are gload_lds write-port, a
// dead axis; the real limiter is the vmcnt(0) drain at every __syncthreads
// (~75% exposed memory wait; delivered staging BW ~12 GB/s/CU). Fix: 4 LDS
// buffers, issue stage(c+2) per chunk, s_waitcnt vmcnt(16) -- NEVER 0 in the
// main loop -- + raw s_barrier. Buffer (c+2)&3 was last read at compute(c-2),
// fenced by chunk c-1's barrier (K = D+2). Back to 256 threads (v4's best
// regime; 2 waves/SIMD was only a band-aid for the drain).
// Numerics identical to v7 (passing): x*2^6, W*2^8 exact scales; hi=RTZ(f),
// lo=RTZ(f-hi) -> product err <= 2^-22|xw|; 2 fp32 MFMA chains folded to
// fp64 every 2 chunks (16-add windows) -> v1-class ~1e-7 error.

typedef __attribute__((ext_vector_type(8))) __fp16 half8;    // 4 VGPR
typedef __attribute__((ext_vector_type(2))) __fp16 half2t;
typedef __attribute__((ext_vector_type(16))) float f32x16;   // 32x32 acc
typedef __attribute__((ext_vector_type(4))) unsigned int uint4v;

#define XSCALE 64.0f
#define WSCALE 256.0f
#define DESCALE (1.0 / 16384.0)

__global__ __launch_bounds__(256, 1)
void gating_kernel(const float* __restrict__ x, const float* __restrict__ W,
                   float* __restrict__ out) {
  // 4 chunk-buffers: x fp32 [64 tok][64 k] (16 KB) + W [64 exp][64 k] (16 KB)
  // each = 128 KB total. lg overlays buf0 after the loop for the epilogue.
  __shared__ union __align__(16) {
    struct { float xs[4][64][KC]; float ws[4][64][KC]; } t;   // 131072 B
    float lg[TPB][E_NUM + 1];                                 // stride 65
  } u;

  const int tid  = threadIdx.x;
  const int tok0 = blockIdx.x * TPB;
  const int lane = tid & 63;
  const int wid  = tid >> 6;            // 0..3
  const int wm   = wid >> 1;            // token half  (32 tokens)
  const int wn   = wid & 1;             // expert half (32 experts)
  const int l31  = lane & 31;
  const int arow = 32 * wm + l31;       // token row for A frags
  const int brow = 32 * wn + l31;       // expert row for B frags
  const int khalf = 32 * (lane >> 5);   // byte offset of this lane's k-octet

  const float* xg = x + (size_t)tok0 * H_DIM;

  // Stage one 16 KB fp32 tile via global_load_lds (width 16): 16 wave-instrs,
  // 4 per wave. Linear LDS dest = I*1024 + lane*16 (HW adds lane*16; base is
  // wave-uniform). instr I covers rows 4I..4I+3 (row = 256 B).
  // Source byte = rowbase + cbyte + (inrow ^ ((row&7)<<4))  [swizzle baked].
  auto stage = [&](const float* gbase, float* lds, int cbyte) {
#pragma unroll
    for (int i = 0; i < 4; ++i) {
      const int I   = wid * 4 + i;                  // wave-uniform
      const int row = 4 * I + (lane >> 4);
      const int inrow = (lane & 15) * 16;
      const char* src = (const char*)(gbase + (size_t)row * H_DIM) + cbyte
                        + (inrow ^ ((row & 7) << 4));
      __builtin_amdgcn_global_load_lds(
          (const __attribute__((address_space(1))) unsigned int*)src,
          (__attribute__((address_space(3))) unsigned int*)((char*)lds + I * 1024),
          16, 0, 0);
    }
  };

  // swizzled 16B frag unit at in-row byte q (same involution as stage)
  auto frag16 = [&](const float* base, int row, int q) -> float4 {
    return *(const float4*)((const char*)base + row * 256
                            + (q ^ ((row & 7) << 4)));
  };

  // fp32x8 -> (hi,lo) fp16x8 via pkrtz; half8 assembled by uint bit-pack.
  auto split8 = [&](float4 v0, float4 v1, float scale, half8& hi, half8& lo) {
    const float f[8] = {v0.x, v0.y, v0.z, v0.w, v1.x, v1.y, v1.z, v1.w};
    unsigned hu[4], lu[4];
#pragma unroll
    for (int i = 0; i < 4; ++i) {
      const float a = f[2 * i] * scale;       // exact (power of 2)
      const float b = f[2 * i + 1] * scale;
      half2t h = __builtin_amdgcn_cvt_pkrtz(a, b);
      const float r0 = a - (float)h.x;        // exact remainder
      const float r1 = b - (float)h.y;
      half2t l = __builtin_amdgcn_cvt_pkrtz(r0, r1);
      hu[i] = __builtin_bit_cast(unsigned, h);
      lu[i] = __builtin_bit_cast(unsigned, l);
    }
    hi = __builtin_bit_cast(half8, (uint4v){hu[0], hu[1], hu[2], hu[3]});
    lo = __builtin_bit_cast(half8, (uint4v){lu[0], lu[1], lu[2], lu[3]});
  };

  // prologue: fill buffers 0 and 1 (8 vmcnt ops per wave per chunk)
  stage(xg, &u.t.xs[0][0][0], 0);
  stage(W,  &u.t.ws[0][0][0], 0);
  stage(xg, &u.t.xs[1][0][0], KC * 4);
  stage(W,  &u.t.ws[1][0][0], KC * 4);

  f32x16 aH, aL;
  double accd[16];
#pragma unroll
  for (int r = 0; r < 16; ++r) { aH[r] = 0.f; aL[r] = 0.f; accd[r] = 0.0; }

  for (int c = 0; c < NCHUNK; ++c) {
    // issue stage(c+2) into buf (c+2)&3: last read at compute(c-2), which
    // chunk c-1's barrier already fenced block-wide (K = D+2 = 4 buffers).
    if (c + 2 < NCHUNK) {
      const int nb = (c + 2) & 3;
      const int cb = (c + 2) * KC * 4;
      stage(xg, &u.t.xs[nb][0][0], cb);
      stage(W,  &u.t.ws[nb][0][0], cb);
    }
    // counted wait: keep the 2 newest chunks' loads (16 instrs) in flight;
    // guarantees own-wave stage(c) landed. Tail peels 8 -> 0.
    if (c + 2 < NCHUNK)      asm volatile("s_waitcnt vmcnt(16)" ::: "memory");
    else if (c + 1 < NCHUNK) asm volatile("s_waitcnt vmcnt(8)"  ::: "memory");
    else                     asm volatile("s_waitcnt vmcnt(0)"  ::: "memory");
    __builtin_amdgcn_s_barrier();   // all waves' stage(c) writes now visible
    asm volatile("" ::: "memory");

    const int b = c & 3;
    const float* xt = &u.t.xs[b][0][0];
    const float* wt = &u.t.ws[b][0][0];

#pragma unroll
    for (int kt = 0; kt < 4; ++kt) {         // 4 k-tiles of 16
      const int q = kt * 64 + khalf;
      half8 ah, al, bh, bl;
      split8(frag16(xt, arow, q), frag16(xt, arow, q + 16), XSCALE, ah, al);
      split8(frag16(wt, brow, q), frag16(wt, brow, q + 16), WSCALE, bh, bl);
      aH = __builtin_amdgcn_mfma_f32_32x32x16_f16(ah, bh, aH, 0, 0, 0);
      aL = __builtin_amdgcn_mfma_f32_32x32x16_f16(al, bh, aL, 0, 0, 0);
      aH = __builtin_amdgcn_mfma_f32_32x32x16_f16(ah, bl, aH, 0, 0, 0);
      aL = __builtin_amdgcn_mfma_f32_32x32x16_f16(al, bl, aL, 0, 0, 0);
    }

    if (c & 1) {   // fp64 fold every 2 chunks: 16-add fp32 windows
#pragma unroll
      for (int r = 0; r < 16; ++r) {
        accd[r] += (double)aH[r] + (double)aL[r];
        aH[r] = 0.f; aL[r] = 0.f;
      }
    }
  }
  __syncthreads();   // full drain + fence before lg overlays buf0

  // C/D layout (HW-verified m74/m101): col = lane&31,
  // row = (reg&3) + 8*(reg>>2) + 4*(lane>>5).
  const int rb = 4 * (lane >> 5);
  float* gate = out + OFF_GATE;
#pragma unroll
  for (int q = 0; q < 4; ++q)
#pragma unroll
    for (int j = 0; j < 4; ++j) {
      const int reg   = 4 * q + j;
      const int row32 = j + 8 * q + rb;
      const float v   = (float)(accd[reg] * DESCALE);   // exact 2^-14
      const int trow  = 32 * wm + row32;
      const int e     = 32 * wn + l31;
      gate[(size_t)(tok0 + trow) * E_NUM + e] = v;   // coalesced 128B/half-wave
      u.lg[trow][e] = v;
    }
  __syncthreads();

  // Phase 2: one thread per token — verbatim from the verified kernel
  // (strict > == jax lowest-index tie-break).
  if (tid < TPB) {
    const int t = tid;
    float vals[TOPK];
    int   idxs[TOPK];
#pragma unroll
    for (int p = 0; p < TOPK; ++p) {
      float best = -INFINITY;
      int   bi   = 0;
      for (int e = 0; e < E_NUM; ++e) {
        const float v = u.lg[t][e];
        if (v > best) { best = v; bi = e; }
      }
      vals[p] = best;
      idxs[p] = bi;
      u.lg[t][bi] = -INFINITY;
    }
    const float m = vals[0];
    float s = 0.f, pr[TOPK];
#pragma unroll
    for (int p = 0; p < TOPK; ++p) { pr[p] = __expf(vals[p] - m); s += pr[p]; }
    const float inv = 1.0f / s;
    for (int e = 0; e < E_NUM; ++e) u.lg[t][e] = 0.f;
#pragma unroll
    for (int p = 0; p < TOPK; ++p) u.lg[t][idxs[p]] = pr[p] * inv;

    float* oidx = out + OFF_IDX + (size_t)(tok0 + t) * TOPK;
#pragma unroll
    for (int p = 0; p < TOPK; ++p) oidx[p] = (float)idxs[p];
  }
  __syncthreads();

  // coalesced writeback of the sparse_probs rows
  float* oprob = out + (size_t)tok0 * E_NUM;
#pragma unroll
  for (int p = 0; p < 16; ++p) {
    const int f = tid + 256 * p;
    oprob[f] = u.lg[f >> 6][f & 63];
  }
}

extern "C" void kernel_launch(void* const* d_in, const int* in_sizes, int n_in,
                              void* d_out, int out_size, void* d_ws, size_t ws_size,
                              hipStream_t stream) {
  const float* x = (const float*)d_in[0];
  const float* W = (const float*)d_in[1];
  float* out = (float*)d_out;
  dim3 grid(N_TOK / TPB);   // 256 blocks -> 1 per CU
  dim3 block(256);          // 4 waves: (token-half, expert-half), full K each
  gating_kernel<<<grid, block, 0, stream>>>(x, W, out);
}

// Round 9
// 395.430 us; speedup vs baseline: 1.1061x; 1.0160x over previous
//
#include <hip/hip_runtime.h>
#include <math.h>

// Problem constants (B=4, S=4096, H=4096, E=64, top_k=8)
#define H_DIM   4096
#define E_NUM   64
#define N_TOK   16384         // B*S
#define TPB     64            // tokens per block
#define KSPLIT  2
#define KHALF   (H_DIM / KSPLIT)   // 2048
#define KC      32            // K chunk (64 chunks per half)
#define NCHUNK  (KHALF / KC)  // 64
#define TOPK    8

// flat output layout: [probs (N_TOK*64)][indices (N_TOK*8)][gate (N_TOK*64)]
#define N_PROBS  (N_TOK * E_NUM)          // 1048576
#define N_IDX    (N_TOK * TOPK)           // 131072
#define OFF_IDX  N_PROBS
#define OFF_GATE (N_PROBS + N_IDX)        // 1179648

// v9: v8's inner loop VERBATIM (fp16 pair-split, 4-buffer counted-vmcnt,
// involution swizzle), re-partitioned for 2 INDEPENDENT blocks per CU:
// K split across 2 blocks (v3's proven partials + reduce kernel), KC=32
// -> LDS 64 KB/block -> 512 blocks = 2/CU in separate barrier domains.
// v8 post-mortem: v4/v6b/v8 all hit ~160us under wildly different intra-
// block pipelines; all stall-hiding so far kept waves in ONE barrier domain
// (correlated stalls -- v7's 2 waves/SIMD gained 0%). Independent blocks
// have uncorrelated stalls; per-CU issue work is unchanged. Clean A/B on
// the overlap axis.
// Numerics: per-half fp64-folded acc -> fp32 partial -> fp32 sum in the
// epilogue kernel = v3's passing scheme; fp16 split terms same as v7/v8.

typedef __attribute__((ext_vector_type(8))) __fp16 half8;    // 4 VGPR
typedef __attribute__((ext_vector_type(2))) __fp16 half2t;
typedef __attribute__((ext_vector_type(16))) float f32x16;   // 32x32 acc
typedef __attribute__((ext_vector_type(4))) unsigned int uint4v;

#define XSCALE 64.0f
#define WSCALE 256.0f
#define DESCALE (1.0 / 16384.0)

__global__ __launch_bounds__(256, 2)
void gemm_part(const float* __restrict__ x, const float* __restrict__ W,
               float* __restrict__ out) {
  // 4 chunk-buffers: x fp32 [64 tok][32 k] (8 KB) + W [64 exp][32 k] (8 KB)
  // = 64 KB total -> 2 blocks/CU (128 KB of 160).
  __shared__ struct __align__(16) {
    float xs[4][64][KC]; float ws[4][64][KC];
  } u;

  const int tid    = threadIdx.x;
  const int tokgrp = blockIdx.x >> 1;
  const int kpart  = blockIdx.x & 1;    // which K half
  const int tok0   = tokgrp * TPB;
  const int lane   = tid & 63;
  const int wid    = tid >> 6;          // 0..3
  const int wm     = wid >> 1;          // token half  (32 tokens)
  const int wn     = wid & 1;           // expert half (32 experts)
  const int l31    = lane & 31;
  const int arow   = 32 * wm + l31;     // token row for A frags
  const int brow   = 32 * wn + l31;     // expert row for B frags
  const int khalf  = 32 * (lane >> 5);  // byte offset of this lane's k-octet

  const float* xg = x + (size_t)tok0 * H_DIM + (size_t)kpart * KHALF;
  const float* wg = W + (size_t)kpart * KHALF;

  // Stage one 8 KB fp32 tile (64 rows x 128 B) via global_load_lds width 16:
  // 8 instrs, 2 per wave. instr I covers rows 8I..8I+7; dest = I*1024 +
  // lane*16 (linear; HW adds lane*16 to the wave-uniform base).
  // Source byte = rowbase + cbyte + (inrow ^ ((row&7)<<4))  [swizzle baked].
  auto stage = [&](const float* gbase, float* lds, int cbyte) {
#pragma unroll
    for (int i = 0; i < 2; ++i) {
      const int I     = wid * 2 + i;                // wave-uniform
      const int row   = 8 * I + (lane >> 3);
      const int inrow = (lane & 7) * 16;
      const char* src = (const char*)(gbase + (size_t)row * H_DIM) + cbyte
                        + (inrow ^ ((row & 7) << 4));
      __builtin_amdgcn_global_load_lds(
          (const __attribute__((address_space(1))) unsigned int*)src,
          (__attribute__((address_space(3))) unsigned int*)((char*)lds + I * 1024),
          16, 0, 0);
    }
  };

  // swizzled 16B frag unit at in-row byte q (same involution; rows = 128 B).
  // Bank check: row stride = 32 words -> r*32%32=0; units (q/16)^(r&7) spread
  // 32 lanes over 8 unit-slots x 4 = the b128 hardware minimum: conflict-free.
  auto frag16 = [&](const float* base, int row, int q) -> float4 {
    return *(const float4*)((const char*)base + row * 128
                            + (q ^ ((row & 7) << 4)));
  };

  // fp32x8 -> (hi,lo) fp16x8 via pkrtz; half8 assembled by uint bit-pack.
  auto split8 = [&](float4 v0, float4 v1, float scale, half8& hi, half8& lo) {
    const float f[8] = {v0.x, v0.y, v0.z, v0.w, v1.x, v1.y, v1.z, v1.w};
    unsigned hu[4], lu[4];
#pragma unroll
    for (int i = 0; i < 4; ++i) {
      const float a = f[2 * i] * scale;       // exact (power of 2)
      const float b = f[2 * i + 1] * scale;
      half2t h = __builtin_amdgcn_cvt_pkrtz(a, b);
      const float r0 = a - (float)h.x;        // exact remainder
      const float r1 = b - (float)h.y;
      half2t l = __builtin_amdgcn_cvt_pkrtz(r0, r1);
      hu[i] = __builtin_bit_cast(unsigned, h);
      lu[i] = __builtin_bit_cast(unsigned, l);
    }
    hi = __builtin_bit_cast(half8, (uint4v){hu[0], hu[1], hu[2], hu[3]});
    lo = __builtin_bit_cast(half8, (uint4v){lu[0], lu[1], lu[2], lu[3]});
  };

  // prologue: fill buffers 0 and 1 (4 vmcnt ops per wave per chunk)
  stage(xg, &u.xs[0][0][0], 0);
  stage(wg, &u.ws[0][0][0], 0);
  stage(xg, &u.xs[1][0][0], KC * 4);
  stage(wg, &u.ws[1][0][0], KC * 4);

  f32x16 aH, aL;
  double accd[16];
#pragma unroll
  for (int r = 0; r < 16; ++r) { aH[r] = 0.f; aL[r] = 0.f; accd[r] = 0.0; }

  for (int c = 0; c < NCHUNK; ++c) {
    // issue stage(c+2) into buf (c+2)&3 = (c-2)&3: last read at compute(c-2),
    // fenced block-wide by the barrier in iteration c-1 (v8 ordering, K=D+2).
    if (c + 2 < NCHUNK) {
      const int nb = (c + 2) & 3;
      const int cb = (c + 2) * KC * 4;
      stage(xg, &u.xs[nb][0][0], cb);
      stage(wg, &u.ws[nb][0][0], cb);
    }
    // counted wait: keep the 2 newest chunks' loads (8 instrs) in flight;
    // guarantees own-wave stage(c) landed. Tail peels 4 -> 0.
    if (c + 2 < NCHUNK)      asm volatile("s_waitcnt vmcnt(8)" ::: "memory");
    else if (c + 1 < NCHUNK) asm volatile("s_waitcnt vmcnt(4)" ::: "memory");
    else                     asm volatile("s_waitcnt vmcnt(0)" ::: "memory");
    __builtin_amdgcn_s_barrier();   // all waves' stage(c) writes now visible
    asm volatile("" ::: "memory");

    const int b = c & 3;
    const float* xt = &u.xs[b][0][0];
    const float* wt = &u.ws[b][0][0];

#pragma unroll
    for (int kt = 0; kt < 2; ++kt) {         // 2 k-tiles of 16
      const int q = kt * 64 + khalf;
      half8 ah, al, bh, bl;
      split8(frag16(xt, arow, q), frag16(xt, arow, q + 16), XSCALE, ah, al);
      split8(frag16(wt, brow, q), frag16(wt, brow, q + 16), WSCALE, bh, bl);
      aH = __builtin_amdgcn_mfma_f32_32x32x16_f16(ah, bh, aH, 0, 0, 0);
      aL = __builtin_amdgcn_mfma_f32_32x32x16_f16(al, bh, aL, 0, 0, 0);
      aH = __builtin_amdgcn_mfma_f32_32x32x16_f16(ah, bl, aH, 0, 0, 0);
      aL = __builtin_amdgcn_mfma_f32_32x32x16_f16(al, bl, aL, 0, 0, 0);
    }

    if (c & 1) {   // fp64 fold every 2 chunks: 8-add fp32 windows
#pragma unroll
      for (int r = 0; r < 16; ++r) {
        accd[r] += (double)aH[r] + (double)aL[r];
        aH[r] = 0.f; aL[r] = 0.f;
      }
    }
  }

  // partial logits, fp32 (v3-proven): K-half 0 -> gate region, K-half 1 ->
  // probs region. C/D layout (HW-verified m74/m101): col = lane&31,
  // row = (reg&3) + 8*(reg>>2) + 4*(lane>>5). Coalesced 128B/half-wave.
  const int rb = 4 * (lane >> 5);
  float* pout = out + (kpart ? 0 : OFF_GATE);
#pragma unroll
  for (int q = 0; q < 4; ++q)
#pragma unroll
    for (int j = 0; j < 4; ++j) {
      const int reg   = 4 * q + j;
      const int row32 = j + 8 * q + rb;
      const float v   = (float)(accd[reg] * DESCALE);   // exact 2^-14
      const int trow  = 32 * wm + row32;
      const int e     = 32 * wn + l31;
      pout[(size_t)(tok0 + trow) * E_NUM + e] = v;
    }
}

// Kernel 2: sum the two partials, write gate, top-k + masked softmax + probs.
// 256 blocks x 64 tokens; verbatim from the verified v3 kernel.
__global__ __launch_bounds__(256, 1)
void reduce_epilogue(float* __restrict__ out) {
  __shared__ float lg[64][E_NUM + 1];   // stride 65 breaks phase-2 conflicts

  const int tid  = threadIdx.x;
  const int tok0 = blockIdx.x * 64;
  const int tx   = tid & 15;            // experts 4*tx..4*tx+3
  const int ty   = tid >> 4;            // tokens  4*ty..4*ty+3

  float* gate = out + OFF_GATE;         // holds partial A, becomes gate output
  float* prob = out;                    // holds partial B, becomes probs output

  // read both partials (coalesced f4), sum, write gate, stage logits in LDS
#pragma unroll
  for (int i = 0; i < 4; ++i) {
    const int t = 4 * ty + i;
    const size_t off = (size_t)(tok0 + t) * E_NUM + 4 * tx;
    const float4 pa = *(const float4*)(gate + off);
    const float4 pb = *(const float4*)(prob + off);
    float4 v = make_float4(pa.x + pb.x, pa.y + pb.y, pa.z + pb.z, pa.w + pb.w);
    *(float4*)(gate + off) = v;
    lg[t][4 * tx + 0] = v.x;
    lg[t][4 * tx + 1] = v.y;
    lg[t][4 * tx + 2] = v.z;
    lg[t][4 * tx + 3] = v.w;
  }
  __syncthreads();

  // Phase 2: one thread per token (wave 0 only).
  if (tid < 64) {
    const int t = tid;
    float vals[TOPK];
    int   idxs[TOPK];
#pragma unroll
    for (int p = 0; p < TOPK; ++p) {
      float best = -INFINITY;
      int   bi   = 0;
      for (int e = 0; e < E_NUM; ++e) {
        const float v = lg[t][e];
        if (v > best) { best = v; bi = e; }   // strict > == jax lowest-index tie-break
      }
      vals[p] = best;
      idxs[p] = bi;
      lg[t][bi] = -INFINITY;
    }
    // softmax over the selected 8 (masked softmax: others are exactly 0)
    const float m = vals[0];
    float s = 0.f, pr[TOPK];
#pragma unroll
    for (int p = 0; p < TOPK; ++p) { pr[p] = __expf(vals[p] - m); s += pr[p]; }
    const float inv = 1.0f / s;
    for (int e = 0; e < E_NUM; ++e) lg[t][e] = 0.f;
#pragma unroll
    for (int p = 0; p < TOPK; ++p) lg[t][idxs[p]] = pr[p] * inv;

    // indices: flat out buffer is fp32 -> write as float (exact for 0..63)
    float* oidx = out + OFF_IDX + (size_t)(tok0 + t) * TOPK;
#pragma unroll
    for (int p = 0; p < TOPK; ++p) oidx[p] = (float)idxs[p];
  }
  __syncthreads();

  // coalesced writeback of the sparse_probs rows (overwrites partial B)
  float* oprob = prob + (size_t)tok0 * E_NUM;
#pragma unroll
  for (int p = 0; p < 16; ++p) {
    const int f = tid + 256 * p;
    oprob[f] = lg[f >> 6][f & 63];
  }
}

extern "C" void kernel_launch(void* const* d_in, const int* in_sizes, int n_in,
                              void* d_out, int out_size, void* d_ws, size_t ws_size,
                              hipStream_t stream) {
  const float* x = (const float*)d_in[0];
  const float* W = (const float*)d_in[1];
  float* out = (float*)d_out;
  // 256 token groups x 2 K-halves = 512 blocks -> 2 independent blocks/CU
  gemm_part<<<dim3(N_TOK / TPB * KSPLIT), dim3(256), 0, stream>>>(x, W, out);
  reduce_epilogue<<<dim3(N_TOK / 64), dim3(256), 0, stream>>>(out);
}